// Round 8
// baseline (87.970 us; speedup 1.0000x reference)
//
#include <hip/hip_runtime.h>

#define GH 52
#define GW 52
#define NB 5
#define NCELL (GH*GW)        // 2704
#define NBOX (NCELL*NB)      // 13520
#define SCALE 8.0f           // 416/52
#define NORMY 416.0f
#define IOU_T 0.4f

// ---- decode tile geometry: 13 wide x 4 tall, 52 blocks (R2/R7-proven) ----
#define TSX 13
#define TSY 4
#define HSX (TSX+2)          // 15
#define HSY (TSY+2)          // 6
#define TBOX (HSX*HSY*NB)    // 450 staged boxes
#define NTX (GW/TSX)         // 4
#define NTY (GH/TSY)         // 13
#define NDEC (NTX*NTY)       // 52 decode blocks

// ---- nms strip geometry (R1-proven phase 1) ----
#define PW2 56               // padded act row stride; strip windows 4B-aligned
#define PR  54               // padded rows
#define PC2 (PR*PW2)         // 3024 B
#define NSTRIP 13            // 4-cell strips per row
#define NTHR (GH*NSTRIP)     // 676 workers
#define BLK 704              // 11 waves
#define K1 12                // phase-1 passes before switching to sparse tail
#define MAGIC 0x5A17C3E9u
#define ROWS52 ((1ull<<52)-1)

// One dispatch: blocks 0..51 decode (coords->out, masks plane-major + scores->ws,
// publish flag), block 52 runs NMS after spinning on the 52 flags. Scores are
// written ONLY by the nms block (sole-writer, replay-safe — R2/R7 proven).
__global__ __launch_bounds__(BLK) void fused_kernel(
        const float* __restrict__ x, float* __restrict__ out,
        unsigned long long* __restrict__ masks,
        float* __restrict__ wscore,
        unsigned int* __restrict__ ready) {
    __shared__ float4 lbox[TBOX];
    __shared__ float  lsc[TBOX];
    __shared__ __align__(8) unsigned char act_s[PC2];
    __shared__ unsigned int rowflag[3][PR];
    __shared__ unsigned long long masks_s[NB * NCELL];   // plane-major copy

    int t = threadIdx.x;

    if (blockIdx.x < NDEC) {
        // ---------------- decode + suppression-mask build ----------------
        int bx0 = (blockIdx.x % NTX) * TSX;
        int by0 = (blockIdx.x / NTX) * TSY;

        if (t < TBOX) {
            int lcell = t / NB, b = t - lcell * NB;
            int lx = lcell % HSX, ly = lcell / HSX;
            int gx = bx0 + lx - 1, gy = by0 + ly - 1;
            float4 bb = make_float4(0.f, 0.f, 0.f, 0.f);
            float s = -1e30f;                  // sentinel: never a predecessor
            if (gx >= 0 && gx < GW && gy >= 0 && gy < GH) {
                const float* p = x + ((size_t)(gy * GW + gx) * NB + b) * 5;
                float c0 = p[0], c1 = p[1], c2 = p[2], c3 = p[3]; s = p[4];
                float cx = (c0 + (float)gx) * SCALE;
                float w  = c2 * SCALE;
                float cy = NORMY - (c1 + (float)gy) * SCALE;
                float h  = c3 * SCALE;
                bb = make_float4(cx - w * 0.5f, cy - h * 0.5f,
                                 cx + w * 0.5f, cy + h * 0.5f);
            }
            lbox[t] = bb; lsc[t] = s;
        }
        __syncthreads();

        if (t < TSX * TSY * NB) {              // 260 interior boxes
            int lcell = t / NB, b = t - lcell * NB;
            int lxi = lcell % TSX, lyi = lcell / TSX;
            int gx = bx0 + lxi, gy = by0 + lyi;
            int lt = ((lyi + 1) * HSX + (lxi + 1)) * NB + b;
            float4 bj = lbox[lt]; float sj = lsc[lt];
            int cell = gy * GW + gx;
            int j = cell * NB + b;
            float areaj = fmaxf(bj.z - bj.x, 0.f) * fmaxf(bj.w - bj.y, 0.f);
            unsigned long long m = 0ull;
            #pragma unroll
            for (int dy = -1; dy <= 1; ++dy)
            #pragma unroll
            for (int dx = -1; dx <= 1; ++dx)
            #pragma unroll
            for (int nb2 = 0; nb2 < NB; ++nb2) {
                int ln = ((lyi + 1 + dy) * HSX + (lxi + 1 + dx)) * NB + nb2;
                int i = j + (dy * GW + dx) * NB + (nb2 - b);
                if (i == j) continue;
                float si = lsc[ln];
                // pri(i) > pri(j): score desc, stable-argsort index-asc tiebreak
                bool earlier = (si > sj) || (si == sj && i < j);
                if (!earlier) continue;
                float4 bi = lbox[ln];
                float iw = fmaxf(fminf(bi.z, bj.z) - fmaxf(bi.x, bj.x), 0.f);
                float ih = fmaxf(fminf(bi.w, bj.w) - fmaxf(bi.y, bj.y), 0.f);
                float inter = iw * ih;
                float areai = fmaxf(bi.z - bi.x, 0.f) * fmaxf(bi.w - bi.y, 0.f);
                float uni = areai + areaj - inter;
                float iou = (uni > 0.f) ? inter / fmaxf(uni, 1e-12f) : 0.f;
                if (iou > IOU_T)
                    m |= 1ull << ((dy + 1) * 15 + (dx + 1) * 5 + nb2);
            }
            masks[b * NCELL + cell] = m;       // plane-major
            out[j * 5 + 0] = bj.x; out[j * 5 + 1] = bj.y;
            out[j * 5 + 2] = bj.z; out[j * 5 + 3] = bj.w;
            wscore[j] = sj;
        }
        __syncthreads();
        if (t == 0) {
            __threadfence();
            __hip_atomic_store(&ready[blockIdx.x], MAGIC,
                               __ATOMIC_RELEASE, __HIP_MEMORY_SCOPE_AGENT);
        }
        return;
    }

    // ============================ nms block ============================
    // Phase 1 (R1-proven): 676 strip workers, K1 gated Jacobi/GS passes burn
    // down the dense early flips in parallel (exact row-dirty gating).
    // Phase 2: wave 0 alone, barrier-free sparse chaotic tail — scalar row-
    // dirty u64, one full-row eval per event (52 lanes), __ballot change
    // detect, dirt -> r-1,r,r+1. Seed = vsmear(last phase-1 row flags): exact
    // per the gating invariant. Empty dirty set == certified fixpoint.
    bool wk = t < NTHR;
    int row = t / NSTRIP;            // 0..51
    int s   = t - row * NSTRIP;      // 0..12
    int gx0 = s * 4;
    int cell0 = row * GW + gx0;
    int l = t & 63, w = t >> 6;

    // init act grid + flags (overlaps decode execution)
    for (int i = t; i < PC2; i += BLK) {
        int py = i / PW2, px = i - py * PW2;
        act_s[i] = (py >= 1 && py <= GH && px >= 1 && px <= GW) ? 0x1F : 0;
    }
    if (t < PR) {
        rowflag[0][t] = 0;
        rowflag[1][t] = 0;
        rowflag[2][t] = (t >= 1 && t <= GH) ? 1u : 0u;   // prev for pass 0: all dirty
    }

    // wait for all decode blocks
    if (t < NDEC) {
        while (__hip_atomic_load(&ready[t], __ATOMIC_ACQUIRE,
                                 __HIP_MEMORY_SCOPE_AGENT) != MAGIC) {}
    }
    __syncthreads();

    // stage masks into LDS (phase 2) and registers (phase 1)
    for (int i = t; i < NB * NCELL; i += BLK) masks_s[i] = masks[i];
    unsigned long long cm[4][NB];
    #pragma unroll
    for (int c = 0; c < 4; ++c)
        #pragma unroll
        for (int b = 0; b < NB; ++b)
            cm[c][b] = wk ? masks[b * NCELL + cell0 + c] : 0ull;
    __syncthreads();

    int p0 = row * PW2 + gx0;            // 4B-aligned window base
    int pc = (row + 1) * PW2 + gx0 + 1;  // own cells' first byte

    auto rdrow = [&](int p) -> unsigned {
        unsigned lo = *(const unsigned int*)(act_s + p);
        unsigned hi = *(const unsigned short*)(act_s + p + 4);
        return (lo & 0x1F)
             | (((lo >> 8)  & 0x1F) << 5)
             | (((lo >> 16) & 0x1F) << 10)
             | (((lo >> 24) & 0x1F) << 15)
             | ((hi & 0x1F) << 20)
             | (((hi >> 8) & 0x1F) << 25);
    };

    // ---------------- phase 1: K1 gated passes (R1 verbatim) ----------------
    bool conv = false;
    int pprev = 2, pcur = 0, pnext = 1;
    for (int pass = 0; pass < K1; ++pass) {
        if (t < PR) rowflag[pnext][t] = 0;
        const unsigned int* prevf = rowflag[pprev];
        bool mych = false;
        if (wk && (prevf[row] | prevf[row + 1] | prevf[row + 2]) != 0u) {
            unsigned r0  = rdrow(p0);
            unsigned r1v = rdrow(p0 + PW2);
            unsigned r2  = rdrow(p0 + 2 * PW2);
            #pragma unroll
            for (int c = 0; c < 4; ++c) {
                unsigned long long V =
                      (unsigned long long)((r0  >> (5 * c)) & 0x7FFF)
                    | ((unsigned long long)((r1v >> (5 * c)) & 0x7FFF) << 15)
                    | ((unsigned long long)((r2  >> (5 * c)) & 0x7FFF) << 30);
                unsigned nb = 0;
                #pragma unroll
                for (int b = 0; b < NB; ++b)
                    nb |= ((V & cm[c][b]) == 0ull ? 1u : 0u) << b;
                unsigned fld = 5u * (c + 1);
                unsigned old = (r1v >> fld) & 0x1Fu;
                if (nb != old) {
                    r1v = (r1v & ~(0x1Fu << fld)) | (nb << fld);  // in-thread GS
                    act_s[pc + c] = (unsigned char)nb;
                    mych = true;
                }
            }
            if (mych) rowflag[pcur][row + 1] = 1u;     // benign all-write-1 race
        }
        if (__syncthreads_count(mych ? 1 : 0) == 0) { conv = true; break; }
        int t0 = pprev; pprev = pcur; pcur = pnext; pnext = t0;
    }

    // ---------------- phase 2: wave-0 barrier-free sparse tail ----------------
    if (w == 0 && !conv) {
        // seed: row r dirty iff any of rows r-1,r,r+1 changed in last pass
        unsigned fr = (l < GH)
            ? (rowflag[pprev][l] | rowflag[pprev][l + 1] | rowflag[pprev][l + 2])
            : 0u;
        unsigned long long dirty = __ballot(fr != 0u) & ROWS52;
        volatile unsigned char* A = act_s;
        bool on = l < GW;
        int guard = 0;
        while (dirty != 0ull && guard < 4096) {
            ++guard;
            int r = __builtin_ctzll(dirty);
            dirty &= dirty - 1;
            bool ch = false;
            if (on) {
                int pcl = (r + 1) * PW2 + l + 1;
                unsigned a00 = A[pcl - PW2 - 1], a01 = A[pcl - PW2], a02 = A[pcl - PW2 + 1];
                unsigned a10 = A[pcl - 1],       a11 = A[pcl],       a12 = A[pcl + 1];
                unsigned a20 = A[pcl + PW2 - 1], a21 = A[pcl + PW2], a22 = A[pcl + PW2 + 1];
                unsigned long long V =
                      (unsigned long long)(a00 | (a01 << 5) | (a02 << 10))
                    | ((unsigned long long)(a10 | (a11 << 5) | (a12 << 10)) << 15)
                    | ((unsigned long long)(a20 | (a21 << 5) | (a22 << 10)) << 30);
                int cell = r * GW + l;
                unsigned nb = (unsigned)((V & masks_s[cell]) == 0ull)
                            | ((unsigned)((V & masks_s[NCELL + cell]) == 0ull) << 1)
                            | ((unsigned)((V & masks_s[2 * NCELL + cell]) == 0ull) << 2)
                            | ((unsigned)((V & masks_s[3 * NCELL + cell]) == 0ull) << 3)
                            | ((unsigned)((V & masks_s[4 * NCELL + cell]) == 0ull) << 4);
                if (nb != a11) { A[pcl] = (unsigned char)nb; ch = true; }
            }
            unsigned long long bal = __ballot(ch);
            if (bal != 0ull) {
                unsigned long long add = (r > 0) ? (7ull << (r - 1)) : 3ull;
                dirty |= add & ROWS52;   // re-arm r-1, r, r+1 (chaotic, exact)
            }
        }
    }
    __syncthreads();                      // waves 1..10 wait here (1 barrier each)

    // writeback: nms block is the sole writer of the score field
    if (wk) {
        #pragma unroll
        for (int c = 0; c < 4; ++c) {
            unsigned bits = act_s[pc + c];
            int j0 = (cell0 + c) * NB;
            #pragma unroll
            for (int b = 0; b < NB; ++b)
                out[(j0 + b) * 5 + 4] = ((bits >> b) & 1u) ? wscore[j0 + b] : 0.0f;
        }
    }
}

extern "C" void kernel_launch(void* const* d_in, const int* in_sizes, int n_in,
                              void* d_out, int out_size, void* d_ws, size_t ws_size,
                              hipStream_t stream) {
    const float* x = (const float*)d_in[0];
    float* out = (float*)d_out;

    // ws: masks u64[NB][NCELL] plane-major (108160 B) | wscore f32[NBOX]
    //     (54080 B) | ready u32[52]
    unsigned long long* masks = (unsigned long long*)d_ws;
    float* wscore = (float*)((char*)d_ws + 108160);
    unsigned int* ready = (unsigned int*)((char*)d_ws + 108160 + 54080);

    fused_kernel<<<NDEC + 1, BLK, 0, stream>>>(x, out, masks, wscore, ready);
}